// Round 4
// baseline (192.000 us; speedup 1.0000x reference)
//
#include <hip/hip_runtime.h>
#include <math.h>

#define DIM      4096
#define KSEL     2048
#define NTHREADS 256
#define VPT      16   // DIM / NTHREADS

// Which f32 silu pipeline to replicate (bit-exact):
//  0 = XLA-CPU: s = 1/(1+cephes_exp_fma(-x)), h = x*s   (FMA-contracted poly)
//  1 = same but NO fma in poly (strict mul/add)
//  2 = old-XLA tanh-form logistic, fma poly
//  3 = old-XLA tanh-form logistic, no-fma poly
//  4 = ocml: h = x*(1/(1+expf(-x)))   [eliminated in R2]
//  5 = ocml: h = x/(1+expf(-x))
#define SILU_VARIANT 0

__device__ __forceinline__ float cephes_expf(float x, bool use_fma) {
    // classic Cephes/Eigen pexp<float>; args here are in [-5.3, 5.3]:
    // no clamp, no denormal path needed.
    const float LOG2EF = 1.44269504088896341f;
    const float C1     = 0.693359375f;        // fx*C1 exact for |fx|<=8
    const float C2     = -2.12194440e-4f;
    float z0 = use_fma ? __builtin_fmaf(x, LOG2EF, 0.5f)
                       : __fadd_rn(__fmul_rn(x, LOG2EF), 0.5f);
    float fx = floorf(z0);
    float r  = __fsub_rn(x, __fmul_rn(fx, C1));      // exact product
    r = use_fma ? __builtin_fmaf(fx, -C2, r)
                : __fsub_rn(r, __fmul_rn(fx, C2));
    float zz = __fmul_rn(r, r);
    float y  = 1.9875691500e-4f;
    if (use_fma) {
        y = __builtin_fmaf(y, r, 1.3981999507e-3f);
        y = __builtin_fmaf(y, r, 8.3334519073e-3f);
        y = __builtin_fmaf(y, r, 4.1665795894e-2f);
        y = __builtin_fmaf(y, r, 1.6666665459e-1f);
        y = __builtin_fmaf(y, r, 5.0000001201e-1f);
        y = __builtin_fmaf(y, zz, r);
    } else {
        y = __fadd_rn(__fmul_rn(y, r), 1.3981999507e-3f);
        y = __fadd_rn(__fmul_rn(y, r), 8.3334519073e-3f);
        y = __fadd_rn(__fmul_rn(y, r), 4.1665795894e-2f);
        y = __fadd_rn(__fmul_rn(y, r), 1.6666665459e-1f);
        y = __fadd_rn(__fmul_rn(y, r), 5.0000001201e-1f);
        y = __fadd_rn(__fmul_rn(y, zz), r);
    }
    y = __fadd_rn(y, 1.0f);
    int n = (int)fx;                                  // exact, fx in [-8,8]
    float scale = __int_as_float((n + 127) << 23);    // 2^n
    return __fmul_rn(y, scale);                       // exact scaling
}

__device__ __forceinline__ float xla_tanhf(float x, bool use_fma) {
    // XLA/Eigen fast tanh rational approx
    const float kClamp = 7.90531110763549805f;
    float cx = fminf(fmaxf(x, -kClamp), kClamp);
    float x2 = __fmul_rn(cx, cx);
    float p, q;
    if (use_fma) {
        p = __builtin_fmaf(x2, -2.76076847742355e-16f, 2.00018790482477e-13f);
        p = __builtin_fmaf(x2, p, -8.60467152213735e-11f);
        p = __builtin_fmaf(x2, p, 5.12229709037114e-08f);
        p = __builtin_fmaf(x2, p, 1.48572235717979e-05f);
        p = __builtin_fmaf(x2, p, 6.37261928875436e-04f);
        p = __builtin_fmaf(x2, p, 4.89352455891786e-03f);
        q = __builtin_fmaf(x2, 1.19825839466702e-06f, 1.18534705686654e-04f);
        q = __builtin_fmaf(x2, q, 2.26843463243900e-03f);
        q = __builtin_fmaf(x2, q, 4.89352518554385e-03f);
    } else {
        p = __fadd_rn(__fmul_rn(x2, -2.76076847742355e-16f), 2.00018790482477e-13f);
        p = __fadd_rn(__fmul_rn(x2, p), -8.60467152213735e-11f);
        p = __fadd_rn(__fmul_rn(x2, p), 5.12229709037114e-08f);
        p = __fadd_rn(__fmul_rn(x2, p), 1.48572235717979e-05f);
        p = __fadd_rn(__fmul_rn(x2, p), 6.37261928875436e-04f);
        p = __fadd_rn(__fmul_rn(x2, p), 4.89352455891786e-03f);
        q = __fadd_rn(__fmul_rn(x2, 1.19825839466702e-06f), 1.18534705686654e-04f);
        q = __fadd_rn(__fmul_rn(x2, q), 2.26843463243900e-03f);
        q = __fadd_rn(__fmul_rn(x2, q), 4.89352518554385e-03f);
    }
    float t = __fdiv_rn(__fmul_rn(cx, p), q);
    return (fabsf(x) < 0.0004f) ? x : t;
}

__device__ __forceinline__ float silu_ref(float x) {
#if SILU_VARIANT == 0
    float e = cephes_expf(-x, true);
    float s = __fdiv_rn(1.0f, __fadd_rn(1.0f, e));
    return __fmul_rn(x, s);
#elif SILU_VARIANT == 1
    float e = cephes_expf(-x, false);
    float s = __fdiv_rn(1.0f, __fadd_rn(1.0f, e));
    return __fmul_rn(x, s);
#elif SILU_VARIANT == 2
    float t = xla_tanhf(__fmul_rn(0.5f, x), true);
    float s = __fadd_rn(0.5f, __fmul_rn(0.5f, t));
    return __fmul_rn(x, s);
#elif SILU_VARIANT == 3
    float t = xla_tanhf(__fmul_rn(0.5f, x), false);
    float s = __fadd_rn(0.5f, __fmul_rn(0.5f, t));
    return __fmul_rn(x, s);
#elif SILU_VARIANT == 4
    return x * (1.0f / (1.0f + expf(-x)));
#else
    return x / (1.0f + expf(-x));
#endif
}

__global__ __launch_bounds__(NTHREADS) void topk_silu_kernel(
    const float* __restrict__ x, float* __restrict__ out)
{
    const int row  = blockIdx.x;
    const int tid  = threadIdx.x;
    const int lane = tid & 63;
    const int wave = tid >> 6;

    const float4* __restrict__ xr4 =
        reinterpret_cast<const float4*>(x + (size_t)row * DIM);
    float4* __restrict__ or4 =
        reinterpret_cast<float4*>(out + (size_t)row * DIM);

    __shared__ int      hist[4][256];
    __shared__ int      wtot[4];
    __shared__ unsigned s_dig;
    __shared__ int      s_krem;

    // ---- load + reference-replicated f32 silu; keys = bits of |h| ----
    float    hv[VPT];
    unsigned ub[VPT];
    #pragma unroll
    for (int j = 0; j < 4; ++j) {
        float4 v = xr4[j * NTHREADS + tid];
        const float* vp = &v.x;
        #pragma unroll
        for (int c4 = 0; c4 < 4; ++c4) {
            float h = silu_ref(vp[c4]);
            hv[j*4+c4] = h;
            ub[j*4+c4] = __float_as_uint(h) & 0x7FFFFFFFu;
        }
    }

    // ---- MSB-first radix select on the f32 keys (K-th largest) ----
    unsigned prefix = 0;
    int      krem   = KSEL;

    #pragma unroll 1
    for (int pass = 0; pass < 4; ++pass) {
        const int shift = 24 - pass * 8;
        hist[0][tid] = 0; hist[1][tid] = 0; hist[2][tid] = 0; hist[3][tid] = 0;
        __syncthreads();

        const unsigned himask = (pass == 0) ? 0u : (0xFFFFFFFFu << (shift + 8));
        #pragma unroll
        for (int r = 0; r < VPT; ++r) {
            unsigned b = ub[r];
            if ((b & himask) == prefix)
                atomicAdd(&hist[wave][(b >> shift) & 255u], 1);
        }
        __syncthreads();

        int c = hist[0][tid] + hist[1][tid] + hist[2][tid] + hist[3][tid];
        int s = c;
        #pragma unroll
        for (int off = 1; off < 64; off <<= 1) {
            int t = __shfl_down(s, off);
            if (lane + off < 64) s += t;
        }
        if (lane == 0) wtot[wave] = s;
        __syncthreads();
        #pragma unroll
        for (int w = 0; w < 4; ++w)
            if (w > wave) s += wtot[w];

        if (s >= krem && s - c < krem) {   // exactly one bin satisfies
            s_dig  = (unsigned)tid;
            s_krem = krem - (s - c);
        }
        __syncthreads();
        prefix |= s_dig << shift;
        krem    = s_krem;
        __syncthreads();
    }

    // ---- keep iff |h| >= thr (bit compare; ties coincide with ref) ----
    const unsigned tb = prefix;
    #pragma unroll
    for (int j = 0; j < 4; ++j) {
        float4 o;
        o.x = (ub[j*4+0] >= tb) ? hv[j*4+0] : 0.0f;
        o.y = (ub[j*4+1] >= tb) ? hv[j*4+1] : 0.0f;
        o.z = (ub[j*4+2] >= tb) ? hv[j*4+2] : 0.0f;
        o.w = (ub[j*4+3] >= tb) ? hv[j*4+3] : 0.0f;
        or4[j * NTHREADS + tid] = o;
    }
}

extern "C" void kernel_launch(void* const* d_in, const int* in_sizes, int n_in,
                              void* d_out, int out_size, void* d_ws, size_t ws_size,
                              hipStream_t stream) {
    const float* x   = (const float*)d_in[0];
    float*       out = (float*)d_out;
    const int rows = in_sizes[0] / DIM;   // 4 * 4096 = 16384
    topk_silu_kernel<<<rows, NTHREADS, 0, stream>>>(x, out);
}

// Round 5
// 131.086 us; speedup vs baseline: 1.4647x; 1.4647x over previous
//
#include <hip/hip_runtime.h>
#include <math.h>

#define DIM      4096
#define KSEL     2048
#define NTHREADS 256
#define VPT      16   // DIM / NTHREADS
#define NREP     16   // histogram replicas (same-address atomic spreading)
#define HSTRIDE  257  // 257 % 32 == 1 -> replicas of a bin on distinct banks

// ---- bit-exact XLA-CPU silu: s = 1/(1+cephes_exp_fma(-x)); h = x*s ----
// Verified absmax == 0.0 in round 4. DO NOT MODIFY.
__device__ __forceinline__ float cephes_expf_fma(float x) {
    const float LOG2EF = 1.44269504088896341f;
    const float C1     = 0.693359375f;
    const float C2     = -2.12194440e-4f;
    float z0 = __builtin_fmaf(x, LOG2EF, 0.5f);
    float fx = floorf(z0);
    float r  = __fsub_rn(x, __fmul_rn(fx, C1));
    r = __builtin_fmaf(fx, -C2, r);
    float zz = __fmul_rn(r, r);
    float y  = 1.9875691500e-4f;
    y = __builtin_fmaf(y, r, 1.3981999507e-3f);
    y = __builtin_fmaf(y, r, 8.3334519073e-3f);
    y = __builtin_fmaf(y, r, 4.1665795894e-2f);
    y = __builtin_fmaf(y, r, 1.6666665459e-1f);
    y = __builtin_fmaf(y, r, 5.0000001201e-1f);
    y = __builtin_fmaf(y, zz, r);
    y = __fadd_rn(y, 1.0f);
    int n = (int)fx;
    float scale = __int_as_float((n + 127) << 23);
    return __fmul_rn(y, scale);
}

__device__ __forceinline__ float silu_ref(float x) {
    float e = cephes_expf_fma(-x);
    float s = __fdiv_rn(1.0f, __fadd_rn(1.0f, e));
    return __fmul_rn(x, s);
}

__global__ __launch_bounds__(NTHREADS) void topk_silu_kernel(
    const float* __restrict__ x, float* __restrict__ out)
{
    const int row  = blockIdx.x;
    const int tid  = threadIdx.x;
    const int lane = tid & 63;
    const int wave = tid >> 6;
    const int rep  = tid & (NREP - 1);

    const float4* __restrict__ xr4 =
        reinterpret_cast<const float4*>(x + (size_t)row * DIM);
    float4* __restrict__ or4 =
        reinterpret_cast<float4*>(out + (size_t)row * DIM);

    __shared__ int      hist[NREP * HSTRIDE];
    __shared__ int      wtot[4];
    __shared__ unsigned s_dig;
    __shared__ int      s_krem;

    // ---- load + bit-exact f32 silu; keys = bits of |h| ----
    float    hv[VPT];
    unsigned ub[VPT];
    #pragma unroll
    for (int j = 0; j < 4; ++j) {
        float4 v = xr4[j * NTHREADS + tid];
        const float* vp = &v.x;
        #pragma unroll
        for (int c4 = 0; c4 < 4; ++c4) {
            float h = silu_ref(vp[c4]);
            hv[j*4+c4] = h;
            ub[j*4+c4] = __float_as_uint(h) & 0x7FFFFFFFu;
        }
    }

    // ---- MSB-first radix select on the f32 keys (K-th largest) ----
    unsigned prefix = 0;
    int      krem   = KSEL;

    #pragma unroll 1
    for (int pass = 0; pass < 4; ++pass) {
        const int shift = 24 - pass * 8;

        // zero all replicas
        #pragma unroll
        for (int i = tid; i < NREP * HSTRIDE; i += NTHREADS)
            hist[i] = 0;
        __syncthreads();

        const unsigned himask = (pass == 0) ? 0u : (0xFFFFFFFFu << (shift + 8));
        #pragma unroll
        for (int r = 0; r < VPT; ++r) {
            unsigned b = ub[r];
            if ((b & himask) == prefix)
                atomicAdd(&hist[rep * HSTRIDE + ((b >> shift) & 255u)], 1);
        }
        __syncthreads();

        // bin count = sum over replicas (conflict-free reads)
        int c = 0;
        #pragma unroll
        for (int g = 0; g < NREP; ++g)
            c += hist[g * HSTRIDE + tid];

        // inclusive suffix-sum across 256 bins
        int s = c;
        #pragma unroll
        for (int off = 1; off < 64; off <<= 1) {
            int t = __shfl_down(s, off);
            if (lane + off < 64) s += t;
        }
        if (lane == 0) wtot[wave] = s;
        __syncthreads();
        #pragma unroll
        for (int w = 0; w < 4; ++w)
            if (w > wave) s += wtot[w];

        if (s >= krem && s - c < krem) {   // exactly one bin satisfies
            s_dig  = (unsigned)tid;
            s_krem = krem - (s - c);
        }
        __syncthreads();
        prefix |= s_dig << shift;
        krem    = s_krem;
        // next pass's zeroing is ordered w.r.t. this read by the barrier
        // after the zero loop; no extra barrier needed here.
    }

    // ---- keep iff |h| >= thr (bit compare; tie sets coincide with ref) ----
    const unsigned tb = prefix;
    #pragma unroll
    for (int j = 0; j < 4; ++j) {
        float4 o;
        o.x = (ub[j*4+0] >= tb) ? hv[j*4+0] : 0.0f;
        o.y = (ub[j*4+1] >= tb) ? hv[j*4+1] : 0.0f;
        o.z = (ub[j*4+2] >= tb) ? hv[j*4+2] : 0.0f;
        o.w = (ub[j*4+3] >= tb) ? hv[j*4+3] : 0.0f;
        or4[j * NTHREADS + tid] = o;
    }
}

extern "C" void kernel_launch(void* const* d_in, const int* in_sizes, int n_in,
                              void* d_out, int out_size, void* d_ws, size_t ws_size,
                              hipStream_t stream) {
    const float* x   = (const float*)d_in[0];
    float*       out = (float*)d_out;
    const int rows = in_sizes[0] / DIM;   // 4 * 4096 = 16384
    topk_silu_kernel<<<rows, NTHREADS, 0, stream>>>(x, out);
}

// Round 6
// 114.916 us; speedup vs baseline: 1.6708x; 1.1407x over previous
//
#include <hip/hip_runtime.h>
#include <math.h>

#define DIM      4096
#define KSEL     2048
#define NTHREADS 256
#define VPT      16            // DIM / NTHREADS
#define NREP     8             // pass-0 histogram replicas
#define HSTRIDE  257           // 257 % 32 == 1 -> replicas of a bin on distinct banks
#define HREP_SZ  (NREP * HSTRIDE)

// ---- bit-exact XLA-CPU silu: s = 1/(1+cephes_exp_fma(-x)); h = x*s ----
// Verified absmax == 0.0 in round 4. DO NOT MODIFY.
__device__ __forceinline__ float cephes_expf_fma(float x) {
    const float LOG2EF = 1.44269504088896341f;
    const float C1     = 0.693359375f;
    const float C2     = -2.12194440e-4f;
    float z0 = __builtin_fmaf(x, LOG2EF, 0.5f);
    float fx = floorf(z0);
    float r  = __fsub_rn(x, __fmul_rn(fx, C1));
    r = __builtin_fmaf(fx, -C2, r);
    float zz = __fmul_rn(r, r);
    float y  = 1.9875691500e-4f;
    y = __builtin_fmaf(y, r, 1.3981999507e-3f);
    y = __builtin_fmaf(y, r, 8.3334519073e-3f);
    y = __builtin_fmaf(y, r, 4.1665795894e-2f);
    y = __builtin_fmaf(y, r, 1.6666665459e-1f);
    y = __builtin_fmaf(y, r, 5.0000001201e-1f);
    y = __builtin_fmaf(y, zz, r);
    y = __fadd_rn(y, 1.0f);
    int n = (int)fx;
    float scale = __int_as_float((n + 127) << 23);
    return __fmul_rn(y, scale);
}

__device__ __forceinline__ float silu_ref(float x) {
    float e = cephes_expf_fma(-x);
    float s = __fdiv_rn(1.0f, __fadd_rn(1.0f, e));
    return __fmul_rn(x, s);
}

__global__ __launch_bounds__(NTHREADS) void topk_silu_kernel(
    const float* __restrict__ x, float* __restrict__ out)
{
    const int row  = blockIdx.x;
    const int tid  = threadIdx.x;
    const int lane = tid & 63;
    const int wave = tid >> 6;

    const float4* __restrict__ xr4 =
        reinterpret_cast<const float4*>(x + (size_t)row * DIM);
    float4* __restrict__ or4 =
        reinterpret_cast<float4*>(out + (size_t)row * DIM);

    __shared__ int      hrep[HREP_SZ];   // pass-0 replicated histogram
    __shared__ int      hist1[256];      // passes 1-3 single histogram
    __shared__ int      wtot[4];
    __shared__ unsigned s_dig;
    __shared__ int      s_krem;

    // ---- load + bit-exact f32 silu; keys = bits of |h| ----
    float    hv[VPT];
    unsigned ub[VPT];
    #pragma unroll
    for (int j = 0; j < 4; ++j) {
        float4 v = xr4[j * NTHREADS + tid];
        const float* vp = &v.x;
        #pragma unroll
        for (int c4 = 0; c4 < 4; ++c4) {
            float h = silu_ref(vp[c4]);
            hv[j*4+c4] = h;
            ub[j*4+c4] = __float_as_uint(h) & 0x7FFFFFFFu;
        }
    }

    // zero all histograms (overlaps the silu/load latency above)
    #pragma unroll
    for (int i = 0; i < (HREP_SZ + NTHREADS - 1) / NTHREADS; ++i) {
        int idx = tid + i * NTHREADS;
        if (idx < HREP_SZ) hrep[idx] = 0;
    }
    hist1[tid] = 0;
    __syncthreads();

    // ---- pass 0: replicated histogram on top byte of |h| bits ----
    const int rep = tid & (NREP - 1);
    #pragma unroll
    for (int r = 0; r < VPT; ++r)
        atomicAdd(&hrep[rep * HSTRIDE + (ub[r] >> 24)], 1);
    __syncthreads();

    int c = 0;
    #pragma unroll
    for (int g = 0; g < NREP; ++g)
        c += hrep[g * HSTRIDE + tid];

    int s = c;
    #pragma unroll
    for (int off = 1; off < 64; off <<= 1) {
        int t = __shfl_down(s, off);
        if (lane + off < 64) s += t;
    }
    if (lane == 0) wtot[wave] = s;
    __syncthreads();
    #pragma unroll
    for (int w = 0; w < 4; ++w)
        if (w > wave) s += wtot[w];

    int krem = KSEL;
    if (s >= krem && s - c < krem) {       // exactly one bin satisfies
        s_dig  = (unsigned)tid;
        s_krem = krem - (s - c);
    }
    __syncthreads();
    unsigned prefix = s_dig << 24;
    krem = s_krem;

    // ---- passes 1-3: few matching elements -> single histogram ----
    #pragma unroll 1
    for (int pass = 1; pass < 4; ++pass) {
        const int shift = 24 - pass * 8;
        const unsigned himask = 0xFFFFFFFFu << (shift + 8);

        #pragma unroll
        for (int r = 0; r < VPT; ++r) {
            unsigned b = ub[r];
            if ((b & himask) == prefix)
                atomicAdd(&hist1[(b >> shift) & 255u], 1);
        }
        __syncthreads();

        c = hist1[tid];
        s = c;
        #pragma unroll
        for (int off = 1; off < 64; off <<= 1) {
            int t = __shfl_down(s, off);
            if (lane + off < 64) s += t;
        }
        if (lane == 0) wtot[wave] = s;
        __syncthreads();
        #pragma unroll
        for (int w = 0; w < 4; ++w)
            if (w > wave) s += wtot[w];

        if (s >= krem && s - c < krem) {
            s_dig  = (unsigned)tid;
            s_krem = krem - (s - c);
        }
        hist1[tid] = 0;   // re-zero for next pass (same-thread, ordered)
        __syncthreads();
        prefix |= s_dig << shift;
        krem    = s_krem;
    }

    // ---- keep iff |h| >= thr (bit compare; tie sets coincide with ref) ----
    const unsigned tb = prefix;
    #pragma unroll
    for (int j = 0; j < 4; ++j) {
        float4 o;
        o.x = (ub[j*4+0] >= tb) ? hv[j*4+0] : 0.0f;
        o.y = (ub[j*4+1] >= tb) ? hv[j*4+1] : 0.0f;
        o.z = (ub[j*4+2] >= tb) ? hv[j*4+2] : 0.0f;
        o.w = (ub[j*4+3] >= tb) ? hv[j*4+3] : 0.0f;
        or4[j * NTHREADS + tid] = o;
    }
}

extern "C" void kernel_launch(void* const* d_in, const int* in_sizes, int n_in,
                              void* d_out, int out_size, void* d_ws, size_t ws_size,
                              hipStream_t stream) {
    const float* x   = (const float*)d_in[0];
    float*       out = (float*)d_out;
    const int rows = in_sizes[0] / DIM;   // 4 * 4096 = 16384
    topk_silu_kernel<<<rows, NTHREADS, 0, stream>>>(x, out);
}